// Round 2
// baseline (889.341 us; speedup 1.0000x reference)
//
#include <hip/hip_runtime.h>
#include <hip/hip_bf16.h>

#define F 128

typedef __attribute__((ext_vector_type(8))) short bf16x8;
typedef __attribute__((ext_vector_type(4))) float f32x4;

// ---------- helpers ----------

__device__ __forceinline__ short f2bf(float f) {
  union { float f; unsigned u; } v; v.f = f;
  unsigned r = (v.u + 0x7FFFu + ((v.u >> 16) & 1u)) >> 16;  // RNE
  return (short)r;
}

__device__ __forceinline__ float bf2f(short s) {
  union { unsigned u; float f; } v;
  v.u = ((unsigned)(unsigned short)s) << 16;
  return v.f;
}

// packed f32x2 -> bf16x2 (v_cvt_pk_bf16_f32 on gfx950)
__device__ __forceinline__ short2 pk2(float a, float b) {
  __hip_bfloat162 p = __float22bfloat162_rn(make_float2(a, b));
  union { __hip_bfloat162 h; short2 s; } u; u.h = p; return u.s;
}

// shifted softplus: softplus(x) - ln(2), numerically stable
__device__ __forceinline__ float sspf(float x) {
  float t = __expf(-fabsf(x));
  return fmaxf(x, 0.0f) + __logf(1.0f + t) - 0.69314718055994530942f;
}

// H/w staging in LDS: 128 rows x 128 bf16, XOR-swizzled in 8-short (16B) chunks
// -> b16 scatter-writes, b128 A-frag reads, and b64 4-col reads all ~conflict-free
__device__ __forceinline__ int h_idx(int row, int k) {
  int chunk = k >> 3;
  int sw = chunk ^ (row & 15);
  return row * 128 + sw * 8 + (k & 7);
}

// B-fragment straight from global (frag-ordered, lane-contiguous, L2-resident)
__device__ __forceinline__ bf16x8 load_bfrag_g(const unsigned short* __restrict__ W,
                                               int nt, int kb, int lane) {
  return *(const bf16x8*)(W + (((nt * 4 + kb) * 64 + lane) << 3));
}

// A-fragment from row-major fp32 global: 8 consecutive floats -> 8 bf16 (packed cvt)
__device__ __forceinline__ bf16x8 load_afrag_f32(const float* __restrict__ p, bool valid) {
  bf16x8 a = {0, 0, 0, 0, 0, 0, 0, 0};
  if (valid) {
    const float4* q = (const float4*)p;
    float4 x0 = q[0], x1 = q[1];
    short2 p0 = pk2(x0.x, x0.y), p1 = pk2(x0.z, x0.w);
    short2 p2 = pk2(x1.x, x1.y), p3 = pk2(x1.z, x1.w);
    a[0] = p0.x; a[1] = p0.y; a[2] = p1.x; a[3] = p1.y;
    a[4] = p2.x; a[5] = p2.y; a[6] = p3.x; a[7] = p3.y;
  }
  return a;
}

// ---------- prep: convert 5 weight matrices to bf16 MFMA-B-fragment order ----------
// B-frag layout for W[k][n] (128x128): frag(nt,kb), lane = ((k>>3)&3)<<4 | (n&15), j = k&7
__global__ void prep_weights(const float* __restrict__ W1, const float* __restrict__ W2,
                             const float* __restrict__ Wi2f, const float* __restrict__ Wf2o,
                             const float* __restrict__ Wd, unsigned short* __restrict__ out) {
  int t = blockIdx.x * 256 + threadIdx.x;  // 5*16384 total
  int m = t >> 14;
  int idx = t & 16383;
  int k = idx >> 7, n = idx & 127;
  const float* W = (m == 0) ? W1 : (m == 1) ? W2 : (m == 2) ? Wi2f : (m == 3) ? Wf2o : Wd;
  float v = W[idx];
  int nt = n >> 4, kb = k >> 5;
  int lane = (((k >> 3) & 3) << 4) | (n & 15);
  int j = k & 7;
  int dst = (((nt * 4 + kb) * 64 + lane) << 3) | j;
  out[(m << 14) + dst] = (unsigned short)f2bf(v);
}

// ---------- f = x @ W_in2fac  (no bias/activation, no LDS at all) ----------
__global__ __launch_bounds__(256, 4) void f_kernel(const float* __restrict__ x,
                                                   const unsigned short* __restrict__ wfrag,
                                                   float* __restrict__ f, int N) {
  const int tid = threadIdx.x;
  const int lane = tid & 63, wv = tid >> 6;
  const int quad = lane >> 4, ln = lane & 15;
  const int r0 = blockIdx.x * 128;
  const unsigned short* gW = wfrag + 2 * 16384;

  bf16x8 a1[2][4];
#pragma unroll
  for (int mt = 0; mt < 2; ++mt) {
    int row = r0 + wv * 32 + mt * 16 + ln;
    bool valid = row < N;
    const float* rp = x + (size_t)row * F + quad * 8;
#pragma unroll
    for (int kb = 0; kb < 4; ++kb) a1[mt][kb] = load_afrag_f32(rp + kb * 32, valid);
  }

#pragma unroll
  for (int nt = 0; nt < 8; ++nt) {
    f32x4 acc0 = {0, 0, 0, 0}, acc1 = {0, 0, 0, 0};
#pragma unroll
    for (int kb = 0; kb < 4; ++kb) {
      bf16x8 b = load_bfrag_g(gW, nt, kb, lane);
      acc0 = __builtin_amdgcn_mfma_f32_16x16x32_bf16(a1[0][kb], b, acc0, 0, 0, 0);
      acc1 = __builtin_amdgcn_mfma_f32_16x16x32_bf16(a1[1][kb], b, acc1, 0, 0, 0);
    }
    int col = nt * 16 + ln;
#pragma unroll
    for (int mt = 0; mt < 2; ++mt) {
#pragma unroll
      for (int r = 0; r < 4; ++r) {
        int row = r0 + wv * 32 + mt * 16 + quad * 4 + r;
        if (row < N) f[(size_t)row * F + col] = (mt == 0) ? acc0[r] : acc1[r];
      }
    }
  }
}

// ---------- fused edge pipeline ----------
// h = ssp(dijk@W1+b1); w = ssp(h@W2+b2); (seg_j = arange -> identity)
// conv[seg_i] += w * f[idx_j]  (seg_i sorted -> run-length reduce + atomics)
__global__ __launch_bounds__(256, 4) void edge_kernel(
    const float* __restrict__ dijk, const int* __restrict__ idx_j, const int* __restrict__ seg_i,
    const float* __restrict__ b1, const float* __restrict__ b2,
    const unsigned short* __restrict__ wfrag, const float* __restrict__ f,
    float* __restrict__ conv, int E) {
  __shared__ short sH[16384];   // 32KB: h (phase 1) then w (phase 2), both bf16, h_idx swizzle
  __shared__ int sIdx[128];
  __shared__ int sSeg[128];

  const int tid = threadIdx.x;
  const int lane = tid & 63, wv = tid >> 6;
  const int quad = lane >> 4, ln = lane & 15;
  const int e0 = blockIdx.x * 128;
  const unsigned short* gW1 = wfrag;
  const unsigned short* gW2 = wfrag + 16384;

  if (tid < 128) {
    int e = e0 + tid;
    sIdx[tid] = (e < E) ? idx_j[e] : 0;
    sSeg[tid] = (e < E) ? seg_i[e] : -1;
  }

  float bias1v[8], bias2v[8];
#pragma unroll
  for (int nt = 0; nt < 8; ++nt) {
    bias1v[nt] = b1[nt * 16 + ln];
    bias2v[nt] = b2[nt * 16 + ln];
  }

  // A1 frags straight from global dijk (each wave owns 32 edge rows)
  bf16x8 a1[2][4];
#pragma unroll
  for (int mt = 0; mt < 2; ++mt) {
    int row = e0 + wv * 32 + mt * 16 + ln;
    bool valid = row < E;
    const float* rp = dijk + (size_t)row * F + quad * 8;
#pragma unroll
    for (int kb = 0; kb < 4; ++kb) a1[mt][kb] = load_afrag_f32(rp + kb * 32, valid);
  }

  // GEMM1: h = ssp(dijk@W1+b1) -> sH (bf16), B-frags from global (L2)
#pragma unroll
  for (int nt = 0; nt < 8; ++nt) {
    f32x4 acc0 = {0, 0, 0, 0}, acc1 = {0, 0, 0, 0};
#pragma unroll
    for (int kb = 0; kb < 4; ++kb) {
      bf16x8 b = load_bfrag_g(gW1, nt, kb, lane);
      acc0 = __builtin_amdgcn_mfma_f32_16x16x32_bf16(a1[0][kb], b, acc0, 0, 0, 0);
      acc1 = __builtin_amdgcn_mfma_f32_16x16x32_bf16(a1[1][kb], b, acc1, 0, 0, 0);
    }
    int col = nt * 16 + ln;
#pragma unroll
    for (int r = 0; r < 4; ++r) {
      sH[h_idx(wv * 32 + quad * 4 + r, col)] = f2bf(sspf(acc0[r] + bias1v[nt]));
      sH[h_idx(wv * 32 + 16 + quad * 4 + r, col)] = f2bf(sspf(acc1[r] + bias1v[nt]));
    }
  }
  __syncthreads();

  // GEMM2 A frags from staged h
  bf16x8 a2[2][4];
#pragma unroll
  for (int mt = 0; mt < 2; ++mt) {
    int row = wv * 32 + mt * 16 + ln;
#pragma unroll
    for (int kb = 0; kb < 4; ++kb)
      a2[mt][kb] = *(const bf16x8*)(sH + h_idx(row, kb * 32 + quad * 8));
  }
  __syncthreads();  // all a2 loaded before w overwrites sH

  // GEMM2: w = ssp(h@W2+b2) -> sH (bf16)
#pragma unroll
  for (int nt = 0; nt < 8; ++nt) {
    f32x4 acc0 = {0, 0, 0, 0}, acc1 = {0, 0, 0, 0};
#pragma unroll
    for (int kb = 0; kb < 4; ++kb) {
      bf16x8 b = load_bfrag_g(gW2, nt, kb, lane);
      acc0 = __builtin_amdgcn_mfma_f32_16x16x32_bf16(a2[0][kb], b, acc0, 0, 0, 0);
      acc1 = __builtin_amdgcn_mfma_f32_16x16x32_bf16(a2[1][kb], b, acc1, 0, 0, 0);
    }
    int col = nt * 16 + ln;
#pragma unroll
    for (int r = 0; r < 4; ++r) {
      sH[h_idx(wv * 32 + quad * 4 + r, col)] = f2bf(sspf(acc0[r] + bias2v[nt]));
      sH[h_idx(wv * 32 + 16 + quad * 4 + r, col)] = f2bf(sspf(acc1[r] + bias2v[nt]));
    }
  }
  __syncthreads();

  // fused gather + multiply + segmented reduction (sorted seg_i):
  // thread owns 4-col group cg, 16-row strip; float4 f-gather, b64 w read, 4 FMA/row
  {
    const int cg = tid & 31;       // column group (4 cols)
    const int r0l = (tid >> 5) * 16;
    const int c0 = cg * 4;
    f32x4 acc = {0, 0, 0, 0};
    int cur = sSeg[r0l];
    for (int r = r0l; r < r0l + 16; ++r) {
      int s = sSeg[r];
      if (s != cur) {
        if (cur >= 0) {
          float* p = conv + (size_t)cur * F + c0;
          atomicAdd(p + 0, acc[0]); atomicAdd(p + 1, acc[1]);
          atomicAdd(p + 2, acc[2]); atomicAdd(p + 3, acc[3]);
        }
        acc[0] = acc[1] = acc[2] = acc[3] = 0.0f;
        cur = s;
      }
      int jrow = sIdx[r];
      int off = r * 128 + ((((c0 >> 3) ^ (r & 15)) << 3)) + (c0 & 7);
      short4 w = *(const short4*)(sH + off);
      float4 fv = *(const float4*)(f + (size_t)jrow * F + c0);
      acc[0] = fmaf(bf2f(w.x), fv.x, acc[0]);
      acc[1] = fmaf(bf2f(w.y), fv.y, acc[1]);
      acc[2] = fmaf(bf2f(w.z), fv.z, acc[2]);
      acc[3] = fmaf(bf2f(w.w), fv.w, acc[3]);
    }
    if (cur >= 0) {
      float* p = conv + (size_t)cur * F + c0;
      atomicAdd(p + 0, acc[0]); atomicAdd(p + 1, acc[1]);
      atomicAdd(p + 2, acc[2]); atomicAdd(p + 3, acc[3]);
    }
  }
}

// ---------- node pipeline: c = ssp(conv@Wf2o + b); v = c@Wd + b; y = x + v ----------
__global__ __launch_bounds__(256, 4) void node_kernel(
    const float* __restrict__ conv, const float* __restrict__ x,
    const float* __restrict__ bf2o, const float* __restrict__ bd,
    const unsigned short* __restrict__ wfrag, float* __restrict__ y,
    float* __restrict__ vout, int N) {
  __shared__ short sC[16384];
  const int tid = threadIdx.x;
  const int lane = tid & 63, wv = tid >> 6;
  const int quad = lane >> 4, ln = lane & 15;
  const int r0 = blockIdx.x * 128;
  const unsigned short* gWa = wfrag + 3 * 16384;
  const unsigned short* gWd = wfrag + 4 * 16384;

  float bfv[8], bdv[8];
#pragma unroll
  for (int nt = 0; nt < 8; ++nt) {
    bfv[nt] = bf2o[nt * 16 + ln];
    bdv[nt] = bd[nt * 16 + ln];
  }

  bf16x8 a1[2][4];
#pragma unroll
  for (int mt = 0; mt < 2; ++mt) {
    int row = r0 + wv * 32 + mt * 16 + ln;
    bool valid = row < N;
    const float* rp = conv + (size_t)row * F + quad * 8;
#pragma unroll
    for (int kb = 0; kb < 4; ++kb) a1[mt][kb] = load_afrag_f32(rp + kb * 32, valid);
  }

  // GEMM1: c = ssp(conv@Wf2o + b) -> sC bf16
#pragma unroll
  for (int nt = 0; nt < 8; ++nt) {
    f32x4 acc0 = {0, 0, 0, 0}, acc1 = {0, 0, 0, 0};
#pragma unroll
    for (int kb = 0; kb < 4; ++kb) {
      bf16x8 b = load_bfrag_g(gWa, nt, kb, lane);
      acc0 = __builtin_amdgcn_mfma_f32_16x16x32_bf16(a1[0][kb], b, acc0, 0, 0, 0);
      acc1 = __builtin_amdgcn_mfma_f32_16x16x32_bf16(a1[1][kb], b, acc1, 0, 0, 0);
    }
    int col = nt * 16 + ln;
#pragma unroll
    for (int r = 0; r < 4; ++r) {
      sC[h_idx(wv * 32 + quad * 4 + r, col)] = f2bf(sspf(acc0[r] + bfv[nt]));
      sC[h_idx(wv * 32 + 16 + quad * 4 + r, col)] = f2bf(sspf(acc1[r] + bfv[nt]));
    }
  }
  __syncthreads();

  bf16x8 a2[2][4];
#pragma unroll
  for (int mt = 0; mt < 2; ++mt) {
    int row = wv * 32 + mt * 16 + ln;
#pragma unroll
    for (int kb = 0; kb < 4; ++kb)
      a2[mt][kb] = *(const bf16x8*)(sC + h_idx(row, kb * 32 + quad * 8));
  }

  // GEMM2: v = c@Wd + bd; y = x + v  (no further LDS use -> no barrier)
#pragma unroll
  for (int nt = 0; nt < 8; ++nt) {
    f32x4 acc0 = {0, 0, 0, 0}, acc1 = {0, 0, 0, 0};
#pragma unroll
    for (int kb = 0; kb < 4; ++kb) {
      bf16x8 b = load_bfrag_g(gWd, nt, kb, lane);
      acc0 = __builtin_amdgcn_mfma_f32_16x16x32_bf16(a2[0][kb], b, acc0, 0, 0, 0);
      acc1 = __builtin_amdgcn_mfma_f32_16x16x32_bf16(a2[1][kb], b, acc1, 0, 0, 0);
    }
    int col = nt * 16 + ln;
#pragma unroll
    for (int mt = 0; mt < 2; ++mt) {
#pragma unroll
      for (int r = 0; r < 4; ++r) {
        int row = r0 + wv * 32 + mt * 16 + quad * 4 + r;
        if (row < N) {
          float v = ((mt == 0) ? acc0[r] : acc1[r]) + bdv[nt];
          size_t o = (size_t)row * F + col;
          y[o] = x[o] + v;
          vout[o] = v;
        }
      }
    }
  }
}

extern "C" void kernel_launch(void* const* d_in, const int* in_sizes, int n_in,
                              void* d_out, int out_size, void* d_ws, size_t ws_size,
                              hipStream_t stream) {
  const float* x    = (const float*)d_in[0];
  const float* dijk = (const float*)d_in[1];
  const int*   idxj = (const int*)d_in[2];
  const int*   segi = (const int*)d_in[3];
  // d_in[4] = seg_j (identity permutation: segment_sum over it is a no-op)
  // d_in[5] = seg_i_sum (== N)
  const float* W1   = (const float*)d_in[6];
  const float* b1   = (const float*)d_in[7];
  const float* W2   = (const float*)d_in[8];
  const float* b2   = (const float*)d_in[9];
  const float* Wi2f = (const float*)d_in[10];
  const float* Wf2o = (const float*)d_in[11];
  const float* bf2o = (const float*)d_in[12];
  const float* Wd   = (const float*)d_in[13];
  const float* bd   = (const float*)d_in[14];

  int N = in_sizes[0] / F;
  int E = in_sizes[1] / F;

  // workspace layout: [5x16384 bf16 weight frags][f: N*F f32][conv: N*F f32]
  unsigned short* wfrag = (unsigned short*)d_ws;
  float* fbuf = (float*)((char*)d_ws + 5 * 16384 * sizeof(unsigned short));
  float* conv = fbuf + (size_t)N * F;

  float* y = (float*)d_out;
  float* vout = y + (size_t)N * F;

  hipMemsetAsync(conv, 0, (size_t)N * F * sizeof(float), stream);
  prep_weights<<<320, 256, 0, stream>>>(W1, W2, Wi2f, Wf2o, Wd, wfrag);

  int nb = (N + 127) / 128;
  int eb = (E + 127) / 128;
  f_kernel<<<nb, 256, 0, stream>>>(x, wfrag, fbuf, N);
  edge_kernel<<<eb, 256, 0, stream>>>(dijk, idxj, segi, b1, b2, wfrag, fbuf, conv, E);
  node_kernel<<<nb, 256, 0, stream>>>(conv, x, bf2o, bd, wfrag, y, vout, N);
}